// Round 1
// baseline (620.044 us; speedup 1.0000x reference)
//
#include <hip/hip_runtime.h>
#include <math.h>

#define SUB 5
#define TNO 201
#define HNO 64
#define TDATA 50000
#define ESYN 2000
#define ISYN 200
#define PAD (TNO/2)          // 100

// padded-C layout constants: per group of 4 columns we store 20 floats + 1 pad
#define QE (ESYN/4)          // 500 float4-groups for E
#define QI (ISYN/4)          // 50 for I
#define CP 21                // padded stride (21 coprime with 32 -> conflict-free)
#define LDSC ((QE+QI)*CP)    // 11550 floats = 46.2 KB

// ---------------------------------------------------------------------------
// Kernel 1: effective conv weights  W_eff[s][c][k] = sum_h ff_w[s,h]*conv_w[s*64+h,c,k]
//           b_eff[s] = ff_b[s] + sum_h ff_w[s,h]*conv_b[s*64+h]
// ---------------------------------------------------------------------------
__global__ void weff_kernel(const float* __restrict__ conv_w,
                            const float* __restrict__ conv_b,
                            const float* __restrict__ ff_w,
                            const float* __restrict__ ff_b,
                            float* __restrict__ Weff,
                            float* __restrict__ beff) {
    int idx = blockIdx.x * blockDim.x + threadIdx.x;
    if (idx < SUB * 2 * TNO) {
        int s   = idx / (2 * TNO);
        int rem = idx - s * (2 * TNO);          // c*201 + k
        float acc = 0.f;
        #pragma unroll 8
        for (int h = 0; h < HNO; ++h)
            acc = fmaf(ff_w[s * HNO + h], conv_w[(size_t)(s * HNO + h) * (2 * TNO) + rem], acc);
        Weff[idx] = acc;
    }
    if (idx < SUB) {
        float acc = ff_b[idx];
        for (int h = 0; h < HNO; ++h)
            acc = fmaf(ff_w[idx * HNO + h], conv_b[idx * HNO + h], acc);
        beff[idx] = acc;
    }
}

// ---------------------------------------------------------------------------
// Kernel 2 (dominant, memory-bound): per-row grouping matmul.
// Each wave owns one row t: reads S_e[t,:] (8KB) + S_i[t,:] (0.8KB) as float4,
// 5 MACs/element against softmax'd C (held in LDS, padded layout), butterfly
// reduce, writes interleaved Sg[t][2s]=E, Sg[t][2s+1]=I.
// Softmax is recomputed per block (tiny; saves a kernel + global round-trip).
// ---------------------------------------------------------------------------
__global__ __launch_bounds__(256) void group_kernel(
        const float* __restrict__ Se, const float* __restrict__ Si,
        const float* __restrict__ rawE, const float* __restrict__ rawI,
        const float* __restrict__ temp,
        float* __restrict__ Sg) {
    __shared__ float ldsC[LDSC];

    // ---- fused softmax over subunit axis, written in padded layout ----
    float invT = 1.0f / temp[0];
    for (int j = threadIdx.x; j < ESYN + ISYN; j += blockDim.x) {
        float v[SUB];
        float* dst;
        if (j < ESYN) {
            #pragma unroll
            for (int s = 0; s < SUB; ++s) v[s] = rawE[s * ESYN + j] * invT;
            dst = ldsC + (j >> 2) * CP + (j & 3) * SUB;
        } else {
            int jj = j - ESYN;
            #pragma unroll
            for (int s = 0; s < SUB; ++s) v[s] = rawI[s * ISYN + jj] * invT;
            dst = ldsC + QE * CP + (jj >> 2) * CP + (jj & 3) * SUB;
        }
        float m = fmaxf(fmaxf(fmaxf(v[0], v[1]), fmaxf(v[2], v[3])), v[4]);
        float sum = 0.f;
        #pragma unroll
        for (int s = 0; s < SUB; ++s) { v[s] = expf(v[s] - m); sum += v[s]; }
        float r = 1.0f / sum;
        #pragma unroll
        for (int s = 0; s < SUB; ++s) dst[s] = v[s] * r;
    }
    __syncthreads();

    const float* lE = ldsC;
    const float* lI = ldsC + QE * CP;
    int wave = threadIdx.x >> 6;
    int lane = threadIdx.x & 63;
    int nwaves = (gridDim.x * blockDim.x) >> 6;

    for (int t = blockIdx.x * (blockDim.x >> 6) + wave; t < TDATA; t += nwaves) {
        float aE0 = 0.f, aE1 = 0.f, aE2 = 0.f, aE3 = 0.f, aE4 = 0.f;
        float aI0 = 0.f, aI1 = 0.f, aI2 = 0.f, aI3 = 0.f, aI4 = 0.f;

        const float4* rE = (const float4*)(Se + (size_t)t * ESYN);
        for (int q = lane; q < QE; q += 64) {
            float4 v = rE[q];
            const float* c = lE + q * CP;
            aE0 = fmaf(v.x, c[0],  aE0); aE1 = fmaf(v.x, c[1],  aE1);
            aE2 = fmaf(v.x, c[2],  aE2); aE3 = fmaf(v.x, c[3],  aE3);
            aE4 = fmaf(v.x, c[4],  aE4);
            aE0 = fmaf(v.y, c[5],  aE0); aE1 = fmaf(v.y, c[6],  aE1);
            aE2 = fmaf(v.y, c[7],  aE2); aE3 = fmaf(v.y, c[8],  aE3);
            aE4 = fmaf(v.y, c[9],  aE4);
            aE0 = fmaf(v.z, c[10], aE0); aE1 = fmaf(v.z, c[11], aE1);
            aE2 = fmaf(v.z, c[12], aE2); aE3 = fmaf(v.z, c[13], aE3);
            aE4 = fmaf(v.z, c[14], aE4);
            aE0 = fmaf(v.w, c[15], aE0); aE1 = fmaf(v.w, c[16], aE1);
            aE2 = fmaf(v.w, c[17], aE2); aE3 = fmaf(v.w, c[18], aE3);
            aE4 = fmaf(v.w, c[19], aE4);
        }

        const float4* rI = (const float4*)(Si + (size_t)t * ISYN);
        if (lane < QI) {
            float4 v = rI[lane];
            const float* c = lI + lane * CP;
            aI0 = fmaf(v.x, c[0],  aI0); aI1 = fmaf(v.x, c[1],  aI1);
            aI2 = fmaf(v.x, c[2],  aI2); aI3 = fmaf(v.x, c[3],  aI3);
            aI4 = fmaf(v.x, c[4],  aI4);
            aI0 = fmaf(v.y, c[5],  aI0); aI1 = fmaf(v.y, c[6],  aI1);
            aI2 = fmaf(v.y, c[7],  aI2); aI3 = fmaf(v.y, c[8],  aI3);
            aI4 = fmaf(v.y, c[9],  aI4);
            aI0 = fmaf(v.z, c[10], aI0); aI1 = fmaf(v.z, c[11], aI1);
            aI2 = fmaf(v.z, c[12], aI2); aI3 = fmaf(v.z, c[13], aI3);
            aI4 = fmaf(v.z, c[14], aI4);
            aI0 = fmaf(v.w, c[15], aI0); aI1 = fmaf(v.w, c[16], aI1);
            aI2 = fmaf(v.w, c[17], aI2); aI3 = fmaf(v.w, c[18], aI3);
            aI4 = fmaf(v.w, c[19], aI4);
        }

        // 64-lane butterfly reduce of 10 partials
        #pragma unroll
        for (int m = 32; m > 0; m >>= 1) {
            aE0 += __shfl_xor(aE0, m); aE1 += __shfl_xor(aE1, m);
            aE2 += __shfl_xor(aE2, m); aE3 += __shfl_xor(aE3, m);
            aE4 += __shfl_xor(aE4, m);
            aI0 += __shfl_xor(aI0, m); aI1 += __shfl_xor(aI1, m);
            aI2 += __shfl_xor(aI2, m); aI3 += __shfl_xor(aI3, m);
            aI4 += __shfl_xor(aI4, m);
        }
        if (lane == 0) {
            float* o = Sg + (size_t)t * 10;
            o[0] = aE0; o[1] = aI0; o[2] = aE1; o[3] = aI1;
            o[4] = aE2; o[5] = aI2; o[6] = aE3; o[7] = aI3;
            o[8] = aE4; o[9] = aI4;
        }
    }
}

// ---------------------------------------------------------------------------
// Kernel 3: effective 10-ch, 201-tap conv + LeakyReLU + root + LeakyReLU + V_o
// Block = 256 outputs; Sg tile staged in LDS with stride 11 (conflict-free).
// ---------------------------------------------------------------------------
#define OTILE 256
#define OROWS (OTILE + TNO - 1)   // 456
#define OSTR 11

__global__ __launch_bounds__(256) void out_kernel(
        const float* __restrict__ Sg, const float* __restrict__ Weff,
        const float* __restrict__ beff, const float* __restrict__ root_w,
        const float* __restrict__ root_b, const float* __restrict__ V_o,
        float* __restrict__ out) {
    __shared__ float sW[SUB * 2 * TNO];   // 2010
    __shared__ float sS[OROWS * OSTR];    // 456*11
    __shared__ float sb[SUB], srw[SUB], sc[2];

    int tid = threadIdx.x;
    int t0  = blockIdx.x * OTILE;

    for (int i = tid; i < SUB * 2 * TNO; i += OTILE) sW[i] = Weff[i];
    if (tid < SUB) { sb[tid] = beff[tid]; srw[tid] = root_w[tid]; }
    if (tid == 0)  { sc[0] = root_b[0];   sc[1] = V_o[0]; }

    for (int i = tid; i < OROWS * 10; i += OTILE) {
        int rr = i / 10, ch = i - rr * 10;
        int rg = t0 - PAD + rr;
        sS[rr * OSTR + ch] = (rg >= 0 && rg < TDATA) ? Sg[(size_t)rg * 10 + ch] : 0.f;
    }
    __syncthreads();

    int t = t0 + tid;
    if (t >= TDATA) return;

    float a0 = sb[0], a1 = sb[1], a2 = sb[2], a3 = sb[3], a4 = sb[4];
    #pragma unroll 2
    for (int k = 0; k < TNO; ++k) {
        const float* r = sS + (tid + k) * OSTR;
        a0 = fmaf(r[0], sW[0 * 402 + k], a0); a0 = fmaf(r[1], sW[0 * 402 + 201 + k], a0);
        a1 = fmaf(r[2], sW[1 * 402 + k], a1); a1 = fmaf(r[3], sW[1 * 402 + 201 + k], a1);
        a2 = fmaf(r[4], sW[2 * 402 + k], a2); a2 = fmaf(r[5], sW[2 * 402 + 201 + k], a2);
        a3 = fmaf(r[6], sW[3 * 402 + k], a3); a3 = fmaf(r[7], sW[3 * 402 + 201 + k], a3);
        a4 = fmaf(r[8], sW[4 * 402 + k], a4); a4 = fmaf(r[9], sW[4 * 402 + 201 + k], a4);
    }
    auto lk = [](float x) { return x > 0.f ? x : 0.01f * x; };
    a0 = lk(a0); a1 = lk(a1); a2 = lk(a2); a3 = lk(a3); a4 = lk(a4);
    float root = a0 * srw[0] + a1 * srw[1] + a2 * srw[2] + a3 * srw[3] + a4 * srw[4] + sc[0];
    out[t] = lk(root) + sc[1];
}

// ---------------------------------------------------------------------------
extern "C" void kernel_launch(void* const* d_in, const int* in_sizes, int n_in,
                              void* d_out, int out_size, void* d_ws, size_t ws_size,
                              hipStream_t stream) {
    (void)in_sizes; (void)n_in; (void)out_size; (void)ws_size;
    const float* Se     = (const float*)d_in[0];
    const float* Si     = (const float*)d_in[1];
    const float* temp   = (const float*)d_in[2];
    const float* rawE   = (const float*)d_in[3];
    const float* rawI   = (const float*)d_in[4];
    const float* conv_w = (const float*)d_in[5];
    const float* conv_b = (const float*)d_in[6];
    const float* ff_w   = (const float*)d_in[7];
    const float* ff_b   = (const float*)d_in[8];
    const float* root_w = (const float*)d_in[9];
    const float* root_b = (const float*)d_in[10];
    const float* V_o    = (const float*)d_in[11];
    float* out = (float*)d_out;

    float* ws   = (float*)d_ws;
    float* Weff = ws;            // 2010 floats
    float* beff = ws + 2016;     // 5
    float* Sg   = ws + 2048;     // 500000 floats (T x 10 interleaved)

    hipLaunchKernelGGL(weff_kernel, dim3(8), dim3(256), 0, stream,
                       conv_w, conv_b, ff_w, ff_b, Weff, beff);
    // 3 blocks/CU (46.2 KB LDS) x 256 CUs = 768 blocks, 1 row per wave grid-strided
    hipLaunchKernelGGL(group_kernel, dim3(768), dim3(256), 0, stream,
                       Se, Si, rawE, rawI, temp, Sg);
    hipLaunchKernelGGL(out_kernel, dim3((TDATA + OTILE - 1) / OTILE), dim3(256), 0, stream,
                       Sg, Weff, beff, root_w, root_b, V_o, out);
}

// Round 2
// 612.484 us; speedup vs baseline: 1.0123x; 1.0123x over previous
//
#include <hip/hip_runtime.h>
#include <math.h>

#define SUB 5
#define TNO 201
#define HNO 64
#define TDATA 50000
#define ESYN 2000
#define ISYN 200
#define PAD (TNO/2)          // 100

// padded-C layout: per group of 4 columns we store 20 floats (+1 pad)
#define QE (ESYN/4)          // 500 float4-groups for E
#define QI (ISYN/4)          // 50 for I
#define CP 21                // stride 21 coprime with 32 -> conflict-free ds_read
#define LDSC ((QE+QI)*CP)    // 11550 floats = 46.2 KB -> 3 blocks/CU

// ---------------------------------------------------------------------------
// Kernel 1: W_eff[s][c][k] = sum_h ff_w[s,h]*conv_w[s*64+h,c,k];  b_eff likewise
// ---------------------------------------------------------------------------
__global__ void weff_kernel(const float* __restrict__ conv_w,
                            const float* __restrict__ conv_b,
                            const float* __restrict__ ff_w,
                            const float* __restrict__ ff_b,
                            float* __restrict__ Weff,
                            float* __restrict__ beff) {
    int idx = blockIdx.x * blockDim.x + threadIdx.x;
    if (idx < SUB * 2 * TNO) {
        int s   = idx / (2 * TNO);
        int rem = idx - s * (2 * TNO);          // c*201 + k
        float acc = 0.f;
        #pragma unroll 8
        for (int h = 0; h < HNO; ++h)
            acc = fmaf(ff_w[s * HNO + h], conv_w[(size_t)(s * HNO + h) * (2 * TNO) + rem], acc);
        Weff[idx] = acc;
    }
    if (idx < SUB) {
        float acc = ff_b[idx];
        for (int h = 0; h < HNO; ++h)
            acc = fmaf(ff_w[idx * HNO + h], conv_b[idx * HNO + h], acc);
        beff[idx] = acc;
    }
}

// ---------------------------------------------------------------------------
// Kernel 2 (dominant): grouping matmul, 4 rows per wave (register blocking).
// Each c[j] LDS read feeds 4 rows -> LDS pipe ~19us << HBM ~70us.
// Fold-tree reduction: 50 shfl per 4 rows instead of 240.
// ---------------------------------------------------------------------------
__device__ inline float elemf(float4 v, int e) {
    switch (e) { case 0: return v.x; case 1: return v.y; case 2: return v.z; default: return v.w; }
}

// combine two accumulators a,b into one register holding (lane&m ? sum(b) : sum(a))
__device__ inline float foldp(float a, float b, int m, int lane) {
    float send = (lane & m) ? a : b;
    float recv = __shfl_xor(send, m);
    return ((lane & m) ? b : a) + recv;
}

template<int CH0>
__device__ inline void fma_block(float (&acc)[4][10],
                                 float4 v0, float4 v1, float4 v2, float4 v3,
                                 const float* c) {
    #pragma unroll
    for (int e = 0; e < 4; ++e) {
        float a0 = elemf(v0, e), a1 = elemf(v1, e), a2 = elemf(v2, e), a3 = elemf(v3, e);
        #pragma unroll
        for (int s = 0; s < 5; ++s) {
            float w = c[e * 5 + s];
            acc[0][2 * s + CH0] = fmaf(a0, w, acc[0][2 * s + CH0]);
            acc[1][2 * s + CH0] = fmaf(a1, w, acc[1][2 * s + CH0]);
            acc[2][2 * s + CH0] = fmaf(a2, w, acc[2][2 * s + CH0]);
            acc[3][2 * s + CH0] = fmaf(a3, w, acc[3][2 * s + CH0]);
        }
    }
}

__global__ __launch_bounds__(256) void group_kernel(
        const float* __restrict__ Se, const float* __restrict__ Si,
        const float* __restrict__ rawE, const float* __restrict__ rawI,
        const float* __restrict__ temp,
        float* __restrict__ Sg) {
    __shared__ float ldsC[LDSC];

    // ---- fused softmax over subunit axis, padded layout ----
    float invT = 1.0f / temp[0];
    for (int j = threadIdx.x; j < ESYN + ISYN; j += blockDim.x) {
        float v[SUB];
        float* dst;
        if (j < ESYN) {
            #pragma unroll
            for (int s = 0; s < SUB; ++s) v[s] = rawE[s * ESYN + j] * invT;
            dst = ldsC + (j >> 2) * CP + (j & 3) * SUB;
        } else {
            int jj = j - ESYN;
            #pragma unroll
            for (int s = 0; s < SUB; ++s) v[s] = rawI[s * ISYN + jj] * invT;
            dst = ldsC + QE * CP + (jj >> 2) * CP + (jj & 3) * SUB;
        }
        float m = fmaxf(fmaxf(fmaxf(v[0], v[1]), fmaxf(v[2], v[3])), v[4]);
        float sum = 0.f;
        #pragma unroll
        for (int s = 0; s < SUB; ++s) { v[s] = expf(v[s] - m); sum += v[s]; }
        float r = 1.0f / sum;
        #pragma unroll
        for (int s = 0; s < SUB; ++s) dst[s] = v[s] * r;
    }
    __syncthreads();

    const float* lE = ldsC;
    const float* lI = ldsC + QE * CP;
    int wave = threadIdx.x >> 6;
    int lane = threadIdx.x & 63;
    int nw   = (gridDim.x * blockDim.x) >> 6;
    int wid  = blockIdx.x * (blockDim.x >> 6) + wave;

    for (int g = wid; g < TDATA / 4; g += nw) {
        int t0 = g * 4;
        float acc[4][10];
        #pragma unroll
        for (int r = 0; r < 4; ++r)
            #pragma unroll
            for (int c = 0; c < 10; ++c) acc[r][c] = 0.f;

        const float4* R0 = (const float4*)(Se + (size_t)(t0 + 0) * ESYN);
        const float4* R1 = (const float4*)(Se + (size_t)(t0 + 1) * ESYN);
        const float4* R2 = (const float4*)(Se + (size_t)(t0 + 2) * ESYN);
        const float4* R3 = (const float4*)(Se + (size_t)(t0 + 3) * ESYN);

        // E: 7 full iterations (q = lane + 64*it < 448+64 <= 511, all < 500 for it<7)
        for (int it = 0; it < 7; ++it) {
            int q = lane + (it << 6);
            float4 v0 = R0[q], v1 = R1[q], v2 = R2[q], v3 = R3[q];
            fma_block<0>(acc, v0, v1, v2, v3, lE + q * CP);
        }
        {   // tail it=7: q in [448,511], valid while q<500 (lanes 0..51)
            int q = lane + 448;
            float4 z = make_float4(0.f, 0.f, 0.f, 0.f);
            float4 v0 = z, v1 = z, v2 = z, v3 = z;
            if (q < QE) { v0 = R0[q]; v1 = R1[q]; v2 = R2[q]; v3 = R3[q]; }
            int qc = (q < QE) ? q : 0;           // LDS addr stays in-bounds; v==0 kills garbage
            fma_block<0>(acc, v0, v1, v2, v3, lE + qc * CP);
        }
        // I: 50 groups, lanes 0..49
        if (lane < QI) {
            const float4* I0 = (const float4*)(Si + (size_t)(t0 + 0) * ISYN);
            const float4* I1 = (const float4*)(Si + (size_t)(t0 + 1) * ISYN);
            const float4* I2 = (const float4*)(Si + (size_t)(t0 + 2) * ISYN);
            const float4* I3 = (const float4*)(Si + (size_t)(t0 + 3) * ISYN);
            float4 v0 = I0[lane], v1 = I1[lane], v2 = I2[lane], v3 = I3[lane];
            fma_block<1>(acc, v0, v1, v2, v3, lI + lane * CP);
        }

        // ---- fold-tree reduction: 40 accs -> 5 regs, then 3-step butterfly ----
        // linear index i = row*10 + ch; after 3 folds reg f3[j] (j=0..4) holds
        // full-coset sum of acc[8j + (lane&7)]; butterfly m=8,16,32 completes it.
        float f1[20], f2[10], f3[5];
        {
            const float* a = &acc[0][0];
            #pragma unroll
            for (int j = 0; j < 20; ++j) f1[j] = foldp(a[2 * j], a[2 * j + 1], 1, lane);
            #pragma unroll
            for (int j = 0; j < 10; ++j) f2[j] = foldp(f1[2 * j], f1[2 * j + 1], 2, lane);
            #pragma unroll
            for (int j = 0; j < 5; ++j)  f3[j] = foldp(f2[2 * j], f2[2 * j + 1], 4, lane);
            #pragma unroll
            for (int j = 0; j < 5; ++j) {
                f3[j] += __shfl_xor(f3[j], 8);
                f3[j] += __shfl_xor(f3[j], 16);
                f3[j] += __shfl_xor(f3[j], 32);
            }
        }
        if (lane < 8) {
            #pragma unroll
            for (int j = 0; j < 5; ++j) {
                int i = 8 * j + lane;           // i in [0,40)
                int r = i / 10, c = i - 10 * r;
                Sg[(size_t)(t0 + r) * 10 + c] = f3[j];
            }
        }
    }
}

// ---------------------------------------------------------------------------
// Kernel 3: effective 10-ch 201-tap conv + LeakyReLU + root + LeakyReLU + V_o.
// Rows staged in LDS (stride 10 floats, float2 reads); Weff read with
// wave-uniform indices from global (scalarizes; 8KB, L1/L2-hot).
// ---------------------------------------------------------------------------
#define OB 128
#define ORS (OB + TNO - 1)   // 328 staged rows

__global__ __launch_bounds__(128) void out_kernel(
        const float* __restrict__ Sg, const float* __restrict__ Weff,
        const float* __restrict__ beff, const float* __restrict__ root_w,
        const float* __restrict__ root_b, const float* __restrict__ V_o,
        float* __restrict__ out) {
    __shared__ float sS[ORS * 10];

    int tid = threadIdx.x;
    int t0  = blockIdx.x * OB;

    for (int i = tid; i < ORS * 5; i += OB) {
        int rr = i / 5, p = i - rr * 5;
        int rg = t0 - PAD + rr;
        float2 val = make_float2(0.f, 0.f);
        if (rg >= 0 && rg < TDATA) val = *(const float2*)(Sg + (size_t)rg * 10 + p * 2);
        *(float2*)(sS + rr * 10 + p * 2) = val;
    }
    __syncthreads();

    int t = t0 + tid;
    if (t >= TDATA) return;

    float acc[SUB];
    #pragma unroll
    for (int s = 0; s < SUB; ++s) acc[s] = beff[s];

    for (int k = 0; k < TNO; ++k) {
        const float* r = sS + (tid + k) * 10;
        #pragma unroll
        for (int s = 0; s < SUB; ++s) {
            float2 ei = *(const float2*)(r + 2 * s);
            acc[s] = fmaf(ei.x, Weff[s * 402 + k],
                     fmaf(ei.y, Weff[s * 402 + 201 + k], acc[s]));
        }
    }
    auto lk = [](float x) { return x > 0.f ? x : 0.01f * x; };
    float root = root_b[0];
    #pragma unroll
    for (int s = 0; s < SUB; ++s) root += lk(acc[s]) * root_w[s];
    out[t] = lk(root) + V_o[0];
}

// ---------------------------------------------------------------------------
extern "C" void kernel_launch(void* const* d_in, const int* in_sizes, int n_in,
                              void* d_out, int out_size, void* d_ws, size_t ws_size,
                              hipStream_t stream) {
    (void)in_sizes; (void)n_in; (void)out_size; (void)ws_size;
    const float* Se     = (const float*)d_in[0];
    const float* Si     = (const float*)d_in[1];
    const float* temp   = (const float*)d_in[2];
    const float* rawE   = (const float*)d_in[3];
    const float* rawI   = (const float*)d_in[4];
    const float* conv_w = (const float*)d_in[5];
    const float* conv_b = (const float*)d_in[6];
    const float* ff_w   = (const float*)d_in[7];
    const float* ff_b   = (const float*)d_in[8];
    const float* root_w = (const float*)d_in[9];
    const float* root_b = (const float*)d_in[10];
    const float* V_o    = (const float*)d_in[11];
    float* out = (float*)d_out;

    float* ws   = (float*)d_ws;
    float* Weff = ws;            // 2010 floats
    float* beff = ws + 2016;     // 5
    float* Sg   = ws + 2048;     // 500000 floats (T x 10 interleaved)

    hipLaunchKernelGGL(weff_kernel, dim3(8), dim3(256), 0, stream,
                       conv_w, conv_b, ff_w, ff_b, Weff, beff);
    // 768 blocks = 3/CU (46.2 KB LDS), 3072 waves, 4 rows per wave per step
    hipLaunchKernelGGL(group_kernel, dim3(768), dim3(256), 0, stream,
                       Se, Si, rawE, rawI, temp, Sg);
    hipLaunchKernelGGL(out_kernel, dim3((TDATA + OB - 1) / OB), dim3(128), 0, stream,
                       Sg, Weff, beff, root_w, root_b, V_o, out);
}